// Round 1
// baseline (931.860 us; speedup 1.0000x reference)
//
#include <hip/hip_runtime.h>
#include <stdint.h>

// Problem constants (from reference): only layers 4 and 11 survive the skip set.
#define Lc   12
#define Bc   32
#define Hc   12
#define Nc   197
#define NNc  (Nc * Nc)      // 38809
#define Kc   9702           // int(38809 * 0.25)
#define NLB  64             // 2 layers * 32 batches

#define HBINS 2048
#define CAP   2048

// ---------------------------------------------------------------------------
// Kernel 1: head-mean.  mean[lb][i*N+j] = (1/12) * sum_h attn[layer][b][h][i][j]
// Sequential h accumulation + divide by 12.0f to match XLA/np f32 semantics.
// ---------------------------------------------------------------------------
__global__ void __launch_bounds__(256) head_mean_kernel(const float* __restrict__ in,
                                                        float* __restrict__ mean) {
    int j  = blockIdx.x * 256 + threadIdx.x;
    int lb = blockIdx.y;            // 0..63 : lsel*32 + b
    if (j >= NNc) return;
    int lsel  = lb >> 5;
    int b     = lb & 31;
    int layer = lsel ? 11 : 4;
    const float* base = in + ((size_t)(layer * Bc + b)) * Hc * NNc + j;
    float acc = 0.0f;
    #pragma unroll
    for (int h = 0; h < Hc; ++h) acc += base[(size_t)h * NNc];
    mean[(size_t)lb * NNc + j] = acc / 12.0f;
}

// ---------------------------------------------------------------------------
// Kernel 2: exact radix select of the Kc-th smallest value per (layer,batch),
// plus tie handling: among elements equal to the threshold, the (Kc - n_less)
// lowest flat indices get zeroed (lax.top_k stable tie-break).
// One 256-thread block per lb.  Values are in [0,1] so uint bit order == float order.
// ---------------------------------------------------------------------------
__global__ void __launch_bounds__(256) select_kernel(const float* __restrict__ mean,
                                                     int* __restrict__ thr_out,
                                                     int* __restrict__ cut_out) {
    const int lb  = blockIdx.x;
    const int tid = threadIdx.x;
    const float* v = mean + (size_t)lb * NNc;

    __shared__ int hist[HBINS];
    __shared__ int chunk[256];
    __shared__ int s_bin, s_cum, s_cnt;
    __shared__ int list[CAP];

    const int shifts[3] = {21, 10, 0};
    const int masks[3]  = {0x7FF, 0x7FF, 0x3FF};

    int kreq = Kc;
    unsigned prefix = 0;   // wave-uniform (derived from shared s_bin each pass)

    for (int pass = 0; pass < 3; ++pass) {
        for (int i = tid; i < HBINS; i += 256) hist[i] = 0;
        __syncthreads();
        for (int i = tid; i < NNc; i += 256) {
            unsigned bits = __float_as_uint(v[i]);
            bool ok = (pass == 0) || ((bits >> shifts[pass - 1]) == prefix);
            if (ok) atomicAdd(&hist[(bits >> shifts[pass]) & masks[pass]], 1);
        }
        __syncthreads();
        // parallel prefix: 8 bins per thread
        int s = 0;
        #pragma unroll
        for (int q = 0; q < 8; ++q) s += hist[tid * 8 + q];
        chunk[tid] = s;
        __syncthreads();
        if (tid == 0) {
            int run = 0;
            for (int t = 0; t < 256; ++t) { int tmp = chunk[t]; chunk[t] = run; run += tmp; }
        }
        __syncthreads();
        {   // locate first bin where cumulative >= kreq (unique crossing)
            int c = chunk[tid];
            #pragma unroll
            for (int q = 0; q < 8; ++q) {
                int h = hist[tid * 8 + q];
                if (c < kreq && c + h >= kreq) { s_bin = tid * 8 + q; s_cum = c; }
                c += h;
            }
        }
        __syncthreads();
        kreq -= s_cum;
        if (pass == 0)      prefix = (unsigned)s_bin;
        else if (pass == 1) prefix = (prefix << 11) | (unsigned)s_bin;
        else                prefix = (prefix << 10) | (unsigned)s_bin;
        __syncthreads();
    }

    // prefix == exact bits of the Kc-th smallest value; kreq == #equals to zero
    if (tid == 0) s_cnt = 0;
    __syncthreads();
    for (int i = tid; i < NNc; i += 256) {
        if (__float_as_uint(v[i]) == prefix) {
            int p = atomicAdd(&s_cnt, 1);
            if (p < CAP) list[p] = i;
        }
    }
    __syncthreads();
    if (tid == 0) {
        int m = s_cnt < CAP ? s_cnt : CAP;
        int t = kreq;          // in [1, m]
        int last = -1;
        for (int s2 = 0; s2 < t && s2 < m; ++s2) {   // t-th smallest index, O(t*m), t tiny
            int mn = 0x7FFFFFFF;
            for (int q = 0; q < m; ++q) { int x = list[q]; if (x > last && x < mn) mn = x; }
            last = mn;
        }
        thr_out[lb] = (int)prefix;
        cut_out[lb] = last;
    }
}

// ---------------------------------------------------------------------------
// Kernel 3: zero selected elements (exempt flat idx 0), (x+I)*0.5, row-normalize.
// In-place on the mean buffer.  One block per row (64*197 blocks).
// ---------------------------------------------------------------------------
__global__ void __launch_bounds__(256) norm_kernel(float* __restrict__ buf,
                                                   const int* __restrict__ thr_arr,
                                                   const int* __restrict__ cut_arr) {
    int row = blockIdx.x;           // 0 .. 64*197-1
    int lb  = row / Nc;
    int i   = row - lb * Nc;
    float thr  = __uint_as_float((unsigned)thr_arr[lb]);
    int cutoff = cut_arr[lb];
    float* rowp = buf + (size_t)lb * NNc + (size_t)i * Nc;

    int j = threadIdx.x;
    float a = 0.0f;
    if (j < Nc) {
        float vv = rowp[j];
        int idx  = i * Nc + j;
        bool zero = (idx != 0) && (vv < thr || (vv == thr && idx <= cutoff));
        float x = zero ? 0.0f : vv;
        a = (x + (i == j ? 1.0f : 0.0f)) * 0.5f;
    }
    // block reduce (4 waves of 64)
    float s = a;
    #pragma unroll
    for (int off = 32; off > 0; off >>= 1) s += __shfl_down(s, off, 64);
    __shared__ float red[4];
    __shared__ float s_tot;
    int wid = threadIdx.x >> 6;
    if ((threadIdx.x & 63) == 0) red[wid] = s;
    __syncthreads();
    if (threadIdx.x == 0) s_tot = red[0] + red[1] + red[2] + red[3];
    __syncthreads();
    if (j < Nc) rowp[j] = a / s_tot;
}

// ---------------------------------------------------------------------------
// Kernel 4: batched fp32 matmul  C[b] = A11n[b] @ A4n[b], 197x197, 16x16 tiles.
// ---------------------------------------------------------------------------
__global__ void __launch_bounds__(256) matmul_kernel(const float* __restrict__ buf,
                                                     float* __restrict__ C) {
    int b  = blockIdx.z;
    const float* A  = buf + (size_t)(32 + b) * NNc;   // layer 11 normalized
    const float* Bm = buf + (size_t)b * NNc;          // layer 4 normalized
    float* Cb = C + (size_t)b * NNc;

    __shared__ float As[16][17];
    __shared__ float Bs[16][17];
    int tx = threadIdx.x, ty = threadIdx.y;
    int i0 = blockIdx.y * 16, j0 = blockIdx.x * 16;
    float acc = 0.0f;
    for (int k0 = 0; k0 < Nc; k0 += 16) {
        int ar = i0 + ty, ac = k0 + tx;
        As[ty][tx] = (ar < Nc && ac < Nc) ? A[ar * Nc + ac] : 0.0f;
        int br = k0 + ty, bc = j0 + tx;
        Bs[ty][tx] = (br < Nc && bc < Nc) ? Bm[br * Nc + bc] : 0.0f;
        __syncthreads();
        #pragma unroll
        for (int kk = 0; kk < 16; ++kk) acc += As[ty][kk] * Bs[kk][tx];
        __syncthreads();
    }
    int i = i0 + ty, j = j0 + tx;
    if (i < Nc && j < Nc) Cb[i * Nc + j] = acc;
}

// ---------------------------------------------------------------------------
extern "C" void kernel_launch(void* const* d_in, const int* in_sizes, int n_in,
                              void* d_out, int out_size, void* d_ws, size_t ws_size,
                              hipStream_t stream) {
    const float* attn = (const float*)d_in[0];
    float* out = (float*)d_out;

    // workspace layout
    float* buf = (float*)d_ws;                                   // 64*38809 floats (~9.94 MB)
    int*   thr = (int*)((char*)d_ws + (size_t)NLB * NNc * sizeof(float));
    int*   cut = thr + NLB;

    dim3 g1((NNc + 255) / 256, NLB);
    head_mean_kernel<<<g1, 256, 0, stream>>>(attn, buf);

    select_kernel<<<NLB, 256, 0, stream>>>(buf, thr, cut);

    norm_kernel<<<NLB * Nc, 256, 0, stream>>>(buf, thr, cut);

    matmul_kernel<<<dim3(13, 13, Bc), dim3(16, 16), 0, stream>>>(buf, out);
}